// Round 4
// baseline (415.559 us; speedup 1.0000x reference)
//
#include <hip/hip_runtime.h>
#include <stdint.h>

typedef __bf16 bf16x8 __attribute__((ext_vector_type(8)));
typedef float  f32x4  __attribute__((ext_vector_type(4)));
typedef float  f32x16 __attribute__((ext_vector_type(16)));

#define QSCALE 0.18033688011112042f  /* 0.125 * log2(e) */

typedef __attribute__((address_space(1))) const void* as1cv;
typedef __attribute__((address_space(3))) void*       as3v;

__device__ __forceinline__ void gload16(const void* g, void* l) {
  __builtin_amdgcn_global_load_lds((as1cv)g, (as3v)l, 16, 0, 0);
}

__device__ __forceinline__ unsigned short f2b(float f) {
  union { float f; unsigned int u; } v; v.f = f;
  unsigned int r = v.u + 0x7fffu + ((v.u >> 16) & 1u);
  return (unsigned short)(r >> 16);
}

__device__ __forceinline__ float b2f(unsigned short s) {
  union { unsigned int u; float f; } v; v.u = (unsigned int)s << 16;
  return v.f;
}

// ---------------- dtype probe ----------------
__global__ void detect_dtype(const unsigned short* __restrict__ x, int* __restrict__ flag) {
  const int t = threadIdx.x;  // 64
  bool big = false;
  for (int i = t; i < 1024; i += 64) {
    float f = b2f(x[i]);
    if (!(fabsf(f) < 1e6f)) big = true;
  }
  if (t == 0) *flag = 0;
  __syncthreads();
  if (__any(big) && t == 0) *flag = 1;
}

// ---------------- x -> bf16 copy/convert ----------------
__global__ __launch_bounds__(256) void convert_x(const void* __restrict__ src,
                                                 unsigned short* __restrict__ dst,
                                                 const int* __restrict__ flag) {
  const int i = blockIdx.x * 256 + threadIdx.x;
  if (*flag) {
    float4 a = ((const float4*)src)[2 * i];
    float4 b = ((const float4*)src)[2 * i + 1];
    union { unsigned short o[8]; uint4 v; } u;
    u.o[0] = f2b(a.x); u.o[1] = f2b(a.y); u.o[2] = f2b(a.z); u.o[3] = f2b(a.w);
    u.o[4] = f2b(b.x); u.o[5] = f2b(b.y); u.o[6] = f2b(b.z); u.o[7] = f2b(b.w);
    ((uint4*)dst)[i] = u.v;
  } else {
    ((uint4*)dst)[i] = ((const uint4*)src)[i];
  }
}

// ---------------- weight transpose ----------------
__global__ __launch_bounds__(256) void transpose_w(const void* __restrict__ src, int R, int C,
                                                   unsigned short* __restrict__ dst,
                                                   const int* __restrict__ flag) {
  __shared__ unsigned short tile[64][72];
  const int t = threadIdx.x;
  const int r = t >> 2;
  const int c0 = (t & 3) << 4;
  const int gr = blockIdx.y * 64 + r;
  const int gc = blockIdx.x * 64 + c0;
  if (*flag) {
    const float* s = (const float*)src + (size_t)gr * C + gc;
#pragma unroll
    for (int j = 0; j < 16; j += 4) {
      float4 v = *(const float4*)(s + j);
      tile[r][c0 + j + 0] = f2b(v.x);
      tile[r][c0 + j + 1] = f2b(v.y);
      tile[r][c0 + j + 2] = f2b(v.z);
      tile[r][c0 + j + 3] = f2b(v.w);
    }
  } else {
    const unsigned short* s = (const unsigned short*)src + (size_t)gr * C + gc;
    *(uint4*)&tile[r][c0]     = *(const uint4*)s;
    *(uint4*)&tile[r][c0 + 8] = *(const uint4*)(s + 8);
  }
  __syncthreads();
  const int c    = t >> 2;
  const int rblk = (t & 3) << 4;
  union { unsigned short o[16]; uint4 v[2]; } u;
#pragma unroll
  for (int j = 0; j < 16; ++j) u.o[j] = tile[rblk + j][c];
  unsigned short* d = dst + (size_t)(blockIdx.x * 64 + c) * R + blockIdx.y * 64 + rblk;
  *(uint4*)d       = u.v[0];
  *(uint4*)(d + 8) = u.v[1];
}

// ---------------- V transpose: QKV[b*S+s][2560+g*64+d] -> VT[(b*8+g)*64+d][s] ----------------
__global__ __launch_bounds__(256) void transpose_v(const unsigned short* __restrict__ qkv,
                                                   unsigned short* __restrict__ vt) {
  __shared__ unsigned short tile[64][72];
  const int t = threadIdx.x;
  const int r = t >> 2, c0 = (t & 3) << 4;
  const int z = blockIdx.z, b = z >> 3, g = z & 7;
  const unsigned short* s = qkv + (size_t)(b * 2048 + blockIdx.x * 64 + r) * 3072 + 2560 + g * 64 + c0;
  *(uint4*)&tile[r][c0]     = *(const uint4*)s;
  *(uint4*)&tile[r][c0 + 8] = *(const uint4*)(s + 8);
  __syncthreads();
  const int c = t >> 2, rblk = (t & 3) << 4;
  union { unsigned short o[16]; uint4 v[2]; } u;
#pragma unroll
  for (int j = 0; j < 16; ++j) u.o[j] = tile[rblk + j][c];
  unsigned short* d = vt + (size_t)(z * 64 + c) * 2048 + blockIdx.x * 64 + rblk;
  *(uint4*)d       = u.v[0];
  *(uint4*)(d + 8) = u.v[1];
}

// ---------------- bf16 GEMM: C[M][N] = A[M][K] @ Bt[N][K]^T ----------------
__global__ __launch_bounds__(256) void gemm_bt(const unsigned short* __restrict__ A,
                                               const unsigned short* __restrict__ Bt,
                                               void* __restrict__ Cv,
                                               int M, int N, int K, int scale_cols,
                                               const int* __restrict__ f32flag) {
  __shared__ unsigned short As[128 * 32];
  __shared__ unsigned short Bs[128 * 32];
  const int t = threadIdx.x;
  const int lane = t & 63;
  const int wave = t >> 6;
  const int wm = wave >> 1, wn = wave & 1;
  const int m0 = blockIdx.y * 128, n0 = blockIdx.x * 128;
  const unsigned short* Ab = A + (size_t)m0 * K;
  const unsigned short* Bb = Bt + (size_t)n0 * K;
  const int fr = lane & 15;
  const int kb2 = (lane >> 4) << 4;
  f32x4 acc[4][4] = {};
  for (int k0 = 0; k0 < K; k0 += 32) {
#pragma unroll
    for (int i = 0; i < 2; ++i) {
      int off = i * 4096 + t * 16;
      int row = off >> 6;
      int cb  = off & 63;
      gload16(Ab + (size_t)row * K + k0 + (cb >> 1), (char*)As + off);
      gload16(Bb + (size_t)row * K + k0 + (cb >> 1), (char*)Bs + off);
    }
    __syncthreads();
    bf16x8 af[4], bfv[4];
#pragma unroll
    for (int i = 0; i < 4; ++i) {
      af[i]  = *(const bf16x8*)((const char*)As + (wm * 64 + i * 16 + fr) * 64 + kb2);
      bfv[i] = *(const bf16x8*)((const char*)Bs + (wn * 64 + i * 16 + fr) * 64 + kb2);
    }
#pragma unroll
    for (int i = 0; i < 4; ++i)
#pragma unroll
      for (int j = 0; j < 4; ++j)
        acc[i][j] = __builtin_amdgcn_mfma_f32_16x16x32_bf16(af[i], bfv[j], acc[i][j], 0, 0, 0);
    __syncthreads();
  }
  const int cm0 = m0 + wm * 64 + ((lane >> 4) << 2);
  const int cn0 = n0 + wn * 64 + fr;
  const bool of32 = f32flag && (*f32flag != 0);
  if (of32) {
    float* C = (float*)Cv;
#pragma unroll
    for (int i = 0; i < 4; ++i)
#pragma unroll
      for (int j = 0; j < 4; ++j) {
        float sc = (cn0 + j * 16 < scale_cols) ? QSCALE : 1.0f;
#pragma unroll
        for (int r = 0; r < 4; ++r)
          C[(size_t)(cm0 + i * 16 + r) * N + (cn0 + j * 16)] = acc[i][j][r] * sc;
      }
  } else {
    unsigned short* C = (unsigned short*)Cv;
#pragma unroll
    for (int i = 0; i < 4; ++i)
#pragma unroll
      for (int j = 0; j < 4; ++j) {
        float sc = (cn0 + j * 16 < scale_cols) ? QSCALE : 1.0f;
#pragma unroll
        for (int r = 0; r < 4; ++r)
          C[(size_t)(cm0 + i * 16 + r) * N + (cn0 + j * 16)] = f2b(acc[i][j][r] * sc);
      }
  }
}

// ---------------- causal GQA flash attention v3: no-LDS, L2-direct, per-wave ----------------
// grid: (S/64, H, B), 128 threads = 2 independent waves (no barriers).
// Wave w owns q-rows [ (31-bid.x)*64 + w*32, +32 ). Lane: q = base + (lane&31), half = lane>>5.
// KV loop in 32-key subtiles; K and V^T fragments loaded directly from global (L2-resident).
__global__ __launch_bounds__(128) void attn_fwd3(const unsigned short* __restrict__ qkv,
                                                 const unsigned short* __restrict__ vt,
                                                 unsigned short* __restrict__ ob) {
  const int t = threadIdx.x, lane = t & 63, w = t >> 6;
  const int half = lane >> 5, q32 = lane & 31;
  const int qt64 = (int)(gridDim.x - 1 - blockIdx.x);
  const int h = blockIdx.y, b = blockIdx.z, g = h >> 2;
  const size_t bS = (size_t)b * 2048;
  const int q_glob = qt64 * 64 + w * 32 + q32;
  const int nks = 2 * qt64 + w + 1;      // 32-key subtiles (causal)
  const size_t vtb = ((size_t)((b << 3) + g)) * 64;

  // Q fragments (pre-scaled by QSCALE in the QKV-GEMM epilogue)
  bf16x8 qf[4];
  {
    const unsigned short* qrow = qkv + (bS + q_glob) * 3072 + h * 64 + half * 8;
#pragma unroll
    for (int c = 0; c < 4; ++c) qf[c] = *(const bf16x8*)(qrow + 16 * c);
  }
  const unsigned short* Kbase = qkv + bS * 3072 + 2048 + g * 64 + half * 8;
  const unsigned short* V0 = vt + (vtb + q32) * 2048 + half * 8;        // d = q32
  const unsigned short* V1 = V0 + 32 * 2048;                            // d = 32+q32

  f32x16 Ot0 = {}, Ot1 = {};
  float m_run = -1e30f, l_run = 0.f;

  for (int ks = 0; ks < nks; ++ks) {
    const int K0 = ks * 32;
    // ---- K fragments straight from global ----
    const unsigned short* kp = Kbase + (size_t)(K0 + q32) * 3072;
    bf16x8 kf0 = *(const bf16x8*)(kp);
    bf16x8 kf1 = *(const bf16x8*)(kp + 16);
    bf16x8 kf2 = *(const bf16x8*)(kp + 32);
    bf16x8 kf3 = *(const bf16x8*)(kp + 48);
    // ---- S^T = K @ Q^T ----
    f32x16 s = {};
    __builtin_amdgcn_s_setprio(1);
    s = __builtin_amdgcn_mfma_f32_32x32x16_bf16(kf0, qf[0], s, 0, 0, 0);
    s = __builtin_amdgcn_mfma_f32_32x32x16_bf16(kf1, qf[1], s, 0, 0, 0);
    s = __builtin_amdgcn_mfma_f32_32x32x16_bf16(kf2, qf[2], s, 0, 0, 0);
    s = __builtin_amdgcn_mfma_f32_32x32x16_bf16(kf3, qf[3], s, 0, 0, 0);
    __builtin_amdgcn_s_setprio(0);
    // ---- causal mask (diagonal subtile only) ----
    if (ks == nks - 1) {
      const int qrel = q32 - 4 * half;
#pragma unroll
      for (int r = 0; r < 16; ++r) {
        const int pat = (r & 3) + 8 * (r >> 2);
        if (pat > qrel) s[r] = -1e30f;
      }
    }
    // ---- online softmax, lane-local + one pair shfl; defer-max (T13) ----
    float pm = s[0];
#pragma unroll
    for (int r = 1; r < 16; ++r) pm = fmaxf(pm, s[r]);
    pm = fmaxf(pm, __shfl_xor(pm, 32, 64));
    if (!__all(pm - m_run <= 8.f)) {
      const float mn = fmaxf(m_run, pm);
      const float corr = exp2f(m_run - mn);
      m_run = mn;
      l_run *= corr;
#pragma unroll
      for (int r = 0; r < 16; ++r) { Ot0[r] *= corr; Ot1[r] *= corr; }
    }
    float rs = 0.f;
#pragma unroll
    for (int r = 0; r < 16; ++r) { float p = exp2f(s[r] - m_run); s[r] = p; rs += p; }
    rs += __shfl_xor(rs, 32, 64);
    l_run += rs;
    // ---- P -> bf16 B-frags via cvt_pk + permlane32_swap ----
    bf16x8 pf[2];
#pragma unroll
    for (int cc = 0; cc < 2; ++cc) {
      unsigned int a01, a23, a45, a67;
      const int bse = cc * 8;
      asm("v_cvt_pk_bf16_f32 %0, %1, %2" : "=v"(a01) : "v"(s[bse + 0]), "v"(s[bse + 1]));
      asm("v_cvt_pk_bf16_f32 %0, %1, %2" : "=v"(a23) : "v"(s[bse + 2]), "v"(s[bse + 3]));
      asm("v_cvt_pk_bf16_f32 %0, %1, %2" : "=v"(a45) : "v"(s[bse + 4]), "v"(s[bse + 5]));
      asm("v_cvt_pk_bf16_f32 %0, %1, %2" : "=v"(a67) : "v"(s[bse + 6]), "v"(s[bse + 7]));
      asm("v_permlane32_swap_b32 %0, %1" : "+v"(a01), "+v"(a45));
      asm("v_permlane32_swap_b32 %0, %1" : "+v"(a23), "+v"(a67));
      union { unsigned int u[4]; bf16x8 v; } fu;
      fu.u[0] = a01; fu.u[1] = a23; fu.u[2] = a45; fu.u[3] = a67;
      pf[cc] = fu.v;
    }
    // ---- V^T fragments straight from global; O^T += V^T @ P^T ----
    bf16x8 vf00 = *(const bf16x8*)(V0 + K0);
    bf16x8 vf01 = *(const bf16x8*)(V0 + K0 + 16);
    bf16x8 vf10 = *(const bf16x8*)(V1 + K0);
    bf16x8 vf11 = *(const bf16x8*)(V1 + K0 + 16);
    __builtin_amdgcn_s_setprio(1);
    Ot0 = __builtin_amdgcn_mfma_f32_32x32x16_bf16(vf00, pf[0], Ot0, 0, 0, 0);
    Ot0 = __builtin_amdgcn_mfma_f32_32x32x16_bf16(vf01, pf[1], Ot0, 0, 0, 0);
    Ot1 = __builtin_amdgcn_mfma_f32_32x32x16_bf16(vf10, pf[0], Ot1, 0, 0, 0);
    Ot1 = __builtin_amdgcn_mfma_f32_32x32x16_bf16(vf11, pf[1], Ot1, 0, 0, 0);
    __builtin_amdgcn_s_setprio(0);
  }
  // ---- epilogue ----
  const float inv = 1.f / l_run;
  unsigned short* orow = ob + (bS + q_glob) * 2048 + h * 64;
#pragma unroll
  for (int j = 0; j < 4; ++j) {
    uint2 pr;
    pr.x = (unsigned int)f2b(Ot0[4 * j + 0] * inv) | ((unsigned int)f2b(Ot0[4 * j + 1] * inv) << 16);
    pr.y = (unsigned int)f2b(Ot0[4 * j + 2] * inv) | ((unsigned int)f2b(Ot0[4 * j + 3] * inv) << 16);
    *(uint2*)(orow + 8 * j + 4 * half) = pr;
    uint2 pr2;
    pr2.x = (unsigned int)f2b(Ot1[4 * j + 0] * inv) | ((unsigned int)f2b(Ot1[4 * j + 1] * inv) << 16);
    pr2.y = (unsigned int)f2b(Ot1[4 * j + 2] * inv) | ((unsigned int)f2b(Ot1[4 * j + 3] * inv) << 16);
    *(uint2*)(orow + 32 + 8 * j + 4 * half) = pr2;
  }
}

extern "C" void kernel_launch(void* const* d_in, const int* in_sizes, int n_in,
                              void* d_out, int out_size, void* d_ws, size_t ws_size,
                              hipStream_t stream) {
  (void)in_sizes; (void)n_in; (void)out_size; (void)ws_size;
  const void* x  = d_in[0];
  const void* wq = d_in[1];
  const void* wk = d_in[2];
  const void* wv = d_in[3];
  const void* wo = d_in[4];
  unsigned short* ws = (unsigned short*)d_ws;

  int* FLAG = (int*)ws;
  unsigned short* WT  = ws + 128;
  unsigned short* WOT = WT  + (size_t)3072 * 2048;
  unsigned short* QKV = WOT + (size_t)2048 * 2048;
  unsigned short* VT  = QKV + (size_t)4096 * 3072;
  unsigned short* OB  = VT  + (size_t)16 * 64 * 2048;
  unsigned short* XB  = OB;  // x-as-bf16 (disjoint lifetime vs OB)

  detect_dtype<<<1, 64, 0, stream>>>((const unsigned short*)x, FLAG);

  transpose_w<<<dim3(32, 32), 256, 0, stream>>>(wq, 2048, 2048, WT, FLAG);
  transpose_w<<<dim3(8, 32), 256, 0, stream>>>(wk, 2048, 512, WT + (size_t)2048 * 2048, FLAG);
  transpose_w<<<dim3(8, 32), 256, 0, stream>>>(wv, 2048, 512, WT + (size_t)2560 * 2048, FLAG);
  transpose_w<<<dim3(32, 32), 256, 0, stream>>>(wo, 2048, 2048, WOT, FLAG);
  convert_x<<<4096, 256, 0, stream>>>(x, XB, FLAG);

  gemm_bt<<<dim3(24, 32), 256, 0, stream>>>(XB, WT, QKV, 4096, 3072, 2048, 2048, nullptr);
  transpose_v<<<dim3(32, 1, 16), 256, 0, stream>>>(QKV, VT);
  attn_fwd3<<<dim3(32, 32, 2), 128, 0, stream>>>(QKV, VT, OB);
  gemm_bt<<<dim3(16, 32), 256, 0, stream>>>(OB, WOT, d_out, 4096, 2048, 2048, 0, FLAG);
}

// Round 5
// 234.787 us; speedup vs baseline: 1.7699x; 1.7699x over previous
//
#include <hip/hip_runtime.h>
#include <stdint.h>

typedef __bf16 bf16x8 __attribute__((ext_vector_type(8)));
typedef float  f32x4  __attribute__((ext_vector_type(4)));
typedef float  f32x16 __attribute__((ext_vector_type(16)));

#define QSCALE 0.18033688011112042f  /* 0.125 * log2(e) */

typedef __attribute__((address_space(1))) const void* as1cv;
typedef __attribute__((address_space(3))) void*       as3v;

__device__ __forceinline__ void gload16(const void* g, void* l) {
  __builtin_amdgcn_global_load_lds((as1cv)g, (as3v)l, 16, 0, 0);
}

__device__ __forceinline__ unsigned short f2b(float f) {
  union { float f; unsigned int u; } v; v.f = f;
  unsigned int r = v.u + 0x7fffu + ((v.u >> 16) & 1u);
  return (unsigned short)(r >> 16);
}

__device__ __forceinline__ float b2f(unsigned short s) {
  union { unsigned int u; float f; } v; v.u = (unsigned int)s << 16;
  return v.f;
}

// raw v_exp_f32 (2^x) — avoids the ocml exp2f call
#if __has_builtin(__builtin_amdgcn_exp2f)
__device__ __forceinline__ float fexp2(float x) { return __builtin_amdgcn_exp2f(x); }
#else
__device__ __forceinline__ float fexp2(float x) {
  float r;
  asm volatile("v_exp_f32 %0, %1\n\ts_nop 1" : "=v"(r) : "v"(x));
  return r;
}
#endif

// ---------------- dtype probe ----------------
__global__ void detect_dtype(const unsigned short* __restrict__ x, int* __restrict__ flag) {
  const int t = threadIdx.x;  // 64
  bool big = false;
  for (int i = t; i < 1024; i += 64) {
    float f = b2f(x[i]);
    if (!(fabsf(f) < 1e6f)) big = true;
  }
  if (t == 0) *flag = 0;
  __syncthreads();
  if (__any(big) && t == 0) *flag = 1;
}

// ---------------- x -> bf16 copy/convert ----------------
__global__ __launch_bounds__(256) void convert_x(const void* __restrict__ src,
                                                 unsigned short* __restrict__ dst,
                                                 const int* __restrict__ flag) {
  const int i = blockIdx.x * 256 + threadIdx.x;
  if (*flag) {
    float4 a = ((const float4*)src)[2 * i];
    float4 b = ((const float4*)src)[2 * i + 1];
    union { unsigned short o[8]; uint4 v; } u;
    u.o[0] = f2b(a.x); u.o[1] = f2b(a.y); u.o[2] = f2b(a.z); u.o[3] = f2b(a.w);
    u.o[4] = f2b(b.x); u.o[5] = f2b(b.y); u.o[6] = f2b(b.z); u.o[7] = f2b(b.w);
    ((uint4*)dst)[i] = u.v;
  } else {
    ((uint4*)dst)[i] = ((const uint4*)src)[i];
  }
}

// ---------------- weight transpose ----------------
__global__ __launch_bounds__(256) void transpose_w(const void* __restrict__ src, int R, int C,
                                                   unsigned short* __restrict__ dst,
                                                   const int* __restrict__ flag) {
  __shared__ unsigned short tile[64][72];
  const int t = threadIdx.x;
  const int r = t >> 2;
  const int c0 = (t & 3) << 4;
  const int gr = blockIdx.y * 64 + r;
  const int gc = blockIdx.x * 64 + c0;
  if (*flag) {
    const float* s = (const float*)src + (size_t)gr * C + gc;
#pragma unroll
    for (int j = 0; j < 16; j += 4) {
      float4 v = *(const float4*)(s + j);
      tile[r][c0 + j + 0] = f2b(v.x);
      tile[r][c0 + j + 1] = f2b(v.y);
      tile[r][c0 + j + 2] = f2b(v.z);
      tile[r][c0 + j + 3] = f2b(v.w);
    }
  } else {
    const unsigned short* s = (const unsigned short*)src + (size_t)gr * C + gc;
    *(uint4*)&tile[r][c0]     = *(const uint4*)s;
    *(uint4*)&tile[r][c0 + 8] = *(const uint4*)(s + 8);
  }
  __syncthreads();
  const int c    = t >> 2;
  const int rblk = (t & 3) << 4;
  union { unsigned short o[16]; uint4 v[2]; } u;
#pragma unroll
  for (int j = 0; j < 16; ++j) u.o[j] = tile[rblk + j][c];
  unsigned short* d = dst + (size_t)(blockIdx.x * 64 + c) * R + blockIdx.y * 64 + rblk;
  *(uint4*)d       = u.v[0];
  *(uint4*)(d + 8) = u.v[1];
}

// ---------------- V transpose: QKV[b*S+s][2560+g*64+d] -> VT[(b*8+g)*64+d][s] ----------------
__global__ __launch_bounds__(256) void transpose_v(const unsigned short* __restrict__ qkv,
                                                   unsigned short* __restrict__ vt) {
  __shared__ unsigned short tile[64][72];
  const int t = threadIdx.x;
  const int r = t >> 2, c0 = (t & 3) << 4;
  const int z = blockIdx.z, b = z >> 3, g = z & 7;
  const unsigned short* s = qkv + (size_t)(b * 2048 + blockIdx.x * 64 + r) * 3072 + 2560 + g * 64 + c0;
  *(uint4*)&tile[r][c0]     = *(const uint4*)s;
  *(uint4*)&tile[r][c0 + 8] = *(const uint4*)(s + 8);
  __syncthreads();
  const int c = t >> 2, rblk = (t & 3) << 4;
  union { unsigned short o[16]; uint4 v[2]; } u;
#pragma unroll
  for (int j = 0; j < 16; ++j) u.o[j] = tile[rblk + j][c];
  unsigned short* d = vt + (size_t)(z * 64 + c) * 2048 + blockIdx.x * 64 + rblk;
  *(uint4*)d       = u.v[0];
  *(uint4*)(d + 8) = u.v[1];
}

// ---------------- bf16 GEMM: C[M][N] = A[M][K] @ Bt[N][K]^T ----------------
__global__ __launch_bounds__(256) void gemm_bt(const unsigned short* __restrict__ A,
                                               const unsigned short* __restrict__ Bt,
                                               void* __restrict__ Cv,
                                               int M, int N, int K, int scale_cols,
                                               const int* __restrict__ f32flag) {
  __shared__ unsigned short As[128 * 32];
  __shared__ unsigned short Bs[128 * 32];
  const int t = threadIdx.x;
  const int lane = t & 63;
  const int wave = t >> 6;
  const int wm = wave >> 1, wn = wave & 1;
  const int m0 = blockIdx.y * 128, n0 = blockIdx.x * 128;
  const unsigned short* Ab = A + (size_t)m0 * K;
  const unsigned short* Bb = Bt + (size_t)n0 * K;
  const int fr = lane & 15;
  const int kb2 = (lane >> 4) << 4;
  f32x4 acc[4][4] = {};
  for (int k0 = 0; k0 < K; k0 += 32) {
#pragma unroll
    for (int i = 0; i < 2; ++i) {
      int off = i * 4096 + t * 16;
      int row = off >> 6;
      int cb  = off & 63;
      gload16(Ab + (size_t)row * K + k0 + (cb >> 1), (char*)As + off);
      gload16(Bb + (size_t)row * K + k0 + (cb >> 1), (char*)Bs + off);
    }
    __syncthreads();
    bf16x8 af[4], bfv[4];
#pragma unroll
    for (int i = 0; i < 4; ++i) {
      af[i]  = *(const bf16x8*)((const char*)As + (wm * 64 + i * 16 + fr) * 64 + kb2);
      bfv[i] = *(const bf16x8*)((const char*)Bs + (wn * 64 + i * 16 + fr) * 64 + kb2);
    }
#pragma unroll
    for (int i = 0; i < 4; ++i)
#pragma unroll
      for (int j = 0; j < 4; ++j)
        acc[i][j] = __builtin_amdgcn_mfma_f32_16x16x32_bf16(af[i], bfv[j], acc[i][j], 0, 0, 0);
    __syncthreads();
  }
  const int cm0 = m0 + wm * 64 + ((lane >> 4) << 2);
  const int cn0 = n0 + wn * 64 + fr;
  const bool of32 = f32flag && (*f32flag != 0);
  if (of32) {
    float* C = (float*)Cv;
#pragma unroll
    for (int i = 0; i < 4; ++i)
#pragma unroll
      for (int j = 0; j < 4; ++j) {
        float sc = (cn0 + j * 16 < scale_cols) ? QSCALE : 1.0f;
#pragma unroll
        for (int r = 0; r < 4; ++r)
          C[(size_t)(cm0 + i * 16 + r) * N + (cn0 + j * 16)] = acc[i][j][r] * sc;
      }
  } else {
    unsigned short* C = (unsigned short*)Cv;
#pragma unroll
    for (int i = 0; i < 4; ++i)
#pragma unroll
      for (int j = 0; j < 4; ++j) {
        float sc = (cn0 + j * 16 < scale_cols) ? QSCALE : 1.0f;
#pragma unroll
        for (int r = 0; r < 4; ++r)
          C[(size_t)(cm0 + i * 16 + r) * N + (cn0 + j * 16)] = f2b(acc[i][j][r] * sc);
      }
  }
}

// ---------------- causal GQA flash attention v4 ----------------
// LDS-staged (fwd2) + 32x32 swapped compute (fwd3) + raw exp2 + defer-max + tile pairing.
// grid (16, H, B), 128 threads = 2 waves. Block handles q-tiles qtA=bid.x and qtB=31-qtA
// (64 q-rows each) -> constant 33 K-tiles of work per block.
// Wave w owns q-rows [qt*64 + w*32, +32). Lane: q32 = lane&31, half = lane>>5.
__global__ __launch_bounds__(128) void attn_fwd4(const unsigned short* __restrict__ qkv,
                                                 const unsigned short* __restrict__ vt,
                                                 unsigned short* __restrict__ ob) {
  __shared__ unsigned short Ks[2][64 * 64];
  __shared__ unsigned short Vs[2][64 * 64];
  const int t = threadIdx.x, lane = t & 63, w = t >> 6;
  const int half = lane >> 5, q32 = lane & 31;
  const int h = blockIdx.y, b = blockIdx.z, g = h >> 2;
  const size_t bS = (size_t)b * 2048;
  const size_t vtb = ((size_t)((b << 3) + g)) * 64;
  const int qtA = blockIdx.x;          // 0..15
  const int qtB = 31 - qtA;            // 16..31

  // staging address precompute (per-thread invariants)
  int rowS[4], dofS[4], cbS[4];
#pragma unroll
  for (int i = 0; i < 4; ++i) {
    int off = i * 2048 + t * 16;
    dofS[i] = off;
    rowS[i] = off >> 7;
    cbS[i]  = (off & 127) ^ ((rowS[i] & 7) << 4);
  }
  const unsigned short* kp0 = qkv + bS * 3072 + 2048 + g * 64;
  const unsigned short* vp0 = vt + vtb * 2048;

  for (int ph = 0; ph < 2; ++ph) {
    if (ph) __syncthreads();           // other wave may still read buffers of phase A
    const int qt = ph ? qtB : qtA;
    const int q_glob = qt * 64 + w * 32 + q32;
    const int skmax = 2 * qt + w;      // this wave's diagonal 32-key subtile index
    const int nkt = qt + 1;            // 64-key tiles to process

    // Q fragments straight from global (pre-scaled by QSCALE in GEMM epilogue)
    bf16x8 qf[4];
    {
      const unsigned short* qrow = qkv + (bS + q_glob) * 3072 + h * 64 + half * 8;
#pragma unroll
      for (int c = 0; c < 4; ++c) qf[c] = *(const bf16x8*)(qrow + 16 * c);
    }
    // staging pointers for tile 0
    const unsigned short* kp[4];
    const unsigned short* vp[4];
#pragma unroll
    for (int i = 0; i < 4; ++i) {
      kp[i] = kp0 + (size_t)rowS[i] * 3072 + (cbS[i] >> 1);
      vp[i] = vp0 + (size_t)rowS[i] * 2048 + (cbS[i] >> 1);
    }
    f32x16 Ot0 = {}, Ot1 = {};
    float m_run = -1e30f, l_run = 0.f;

    // prologue: stage tile 0 into buf 0
#pragma unroll
    for (int i = 0; i < 4; ++i) {
      gload16(kp[i], (char*)Ks[0] + dofS[i]);
      gload16(vp[i], (char*)Vs[0] + dofS[i]);
      kp[i] += 64 * 3072;
      vp[i] += 64;
    }
    int cur = 0;
    for (int kt = 0; kt < nkt; ++kt) {
      __syncthreads();                 // staging of buf[cur] drained; prior reads done
      if (kt + 1 < nkt) {
#pragma unroll
        for (int i = 0; i < 4; ++i) {
          gload16(kp[i], (char*)Ks[cur ^ 1] + dofS[i]);
          gload16(vp[i], (char*)Vs[cur ^ 1] + dofS[i]);
          kp[i] += 64 * 3072;
          vp[i] += 64;
        }
      }
      const char* Kb = (const char*)Ks[cur];
      const char* Vb = (const char*)Vs[cur];
#pragma unroll
      for (int j = 0; j < 2; ++j) {
        const int sk = 2 * kt + j;
        if (sk <= skmax) {
          // ---- K frags from LDS; S^T = K @ Q^T ----
          const int kr = j * 32 + q32;
          const int ksw = (kr & 7) << 4;
          bf16x8 kf0 = *(const bf16x8*)(Kb + kr * 128 + ((16 * half) ^ ksw));
          bf16x8 kf1 = *(const bf16x8*)(Kb + kr * 128 + ((32 + 16 * half) ^ ksw));
          bf16x8 kf2 = *(const bf16x8*)(Kb + kr * 128 + ((64 + 16 * half) ^ ksw));
          bf16x8 kf3 = *(const bf16x8*)(Kb + kr * 128 + ((96 + 16 * half) ^ ksw));
          f32x16 s = {};
          __builtin_amdgcn_s_setprio(1);
          s = __builtin_amdgcn_mfma_f32_32x32x16_bf16(kf0, qf[0], s, 0, 0, 0);
          s = __builtin_amdgcn_mfma_f32_32x32x16_bf16(kf1, qf[1], s, 0, 0, 0);
          s = __builtin_amdgcn_mfma_f32_32x32x16_bf16(kf2, qf[2], s, 0, 0, 0);
          s = __builtin_amdgcn_mfma_f32_32x32x16_bf16(kf3, qf[3], s, 0, 0, 0);
          __builtin_amdgcn_s_setprio(0);
          // ---- causal mask (diagonal subtile only) ----
          if (sk == skmax) {
            const int qrel = q32 - 4 * half;
#pragma unroll
            for (int r = 0; r < 16; ++r) {
              const int pat = (r & 3) + 8 * (r >> 2);
              if (pat > qrel) s[r] = -1e30f;
            }
          }
          // ---- online softmax: lane-local + one pair shfl; defer-max ----
          float pm = s[0];
#pragma unroll
          for (int r = 1; r < 16; ++r) pm = fmaxf(pm, s[r]);
          pm = fmaxf(pm, __shfl_xor(pm, 32, 64));
          if (!__all(pm - m_run <= 8.f)) {
            const float mn = fmaxf(m_run, pm);
            const float corr = fexp2(m_run - mn);
            m_run = mn;
            l_run *= corr;
#pragma unroll
            for (int r = 0; r < 16; ++r) { Ot0[r] *= corr; Ot1[r] *= corr; }
          }
          float rs = 0.f;
#pragma unroll
          for (int r = 0; r < 16; ++r) { float p = fexp2(s[r] - m_run); s[r] = p; rs += p; }
          rs += __shfl_xor(rs, 32, 64);
          l_run += rs;
          // ---- P -> bf16 B-frags via cvt_pk + permlane32_swap ----
          bf16x8 pf[2];
#pragma unroll
          for (int cc = 0; cc < 2; ++cc) {
            unsigned int a01, a23, a45, a67;
            const int bse = cc * 8;
            asm("v_cvt_pk_bf16_f32 %0, %1, %2" : "=v"(a01) : "v"(s[bse + 0]), "v"(s[bse + 1]));
            asm("v_cvt_pk_bf16_f32 %0, %1, %2" : "=v"(a23) : "v"(s[bse + 2]), "v"(s[bse + 3]));
            asm("v_cvt_pk_bf16_f32 %0, %1, %2" : "=v"(a45) : "v"(s[bse + 4]), "v"(s[bse + 5]));
            asm("v_cvt_pk_bf16_f32 %0, %1, %2" : "=v"(a67) : "v"(s[bse + 6]), "v"(s[bse + 7]));
            asm("v_permlane32_swap_b32 %0, %1" : "+v"(a01), "+v"(a45));
            asm("v_permlane32_swap_b32 %0, %1" : "+v"(a23), "+v"(a67));
            union { unsigned int u[4]; bf16x8 v; } fu;
            fu.u[0] = a01; fu.u[1] = a23; fu.u[2] = a45; fu.u[3] = a67;
            pf[cc] = fu.v;
          }
          // ---- V^T frags from LDS; O^T += V^T @ P^T ----
          const int vsw0 = (q32 & 7) << 4;
          const int cbase = 64 * j + 16 * half;
          bf16x8 vf00 = *(const bf16x8*)(Vb + q32 * 128 + (cbase ^ vsw0));
          bf16x8 vf01 = *(const bf16x8*)(Vb + q32 * 128 + ((cbase + 32) ^ vsw0));
          bf16x8 vf10 = *(const bf16x8*)(Vb + (32 + q32) * 128 + (cbase ^ vsw0));
          bf16x8 vf11 = *(const bf16x8*)(Vb + (32 + q32) * 128 + ((cbase + 32) ^ vsw0));
          __builtin_amdgcn_s_setprio(1);
          Ot0 = __builtin_amdgcn_mfma_f32_32x32x16_bf16(vf00, pf[0], Ot0, 0, 0, 0);
          Ot0 = __builtin_amdgcn_mfma_f32_32x32x16_bf16(vf01, pf[1], Ot0, 0, 0, 0);
          Ot1 = __builtin_amdgcn_mfma_f32_32x32x16_bf16(vf10, pf[0], Ot1, 0, 0, 0);
          Ot1 = __builtin_amdgcn_mfma_f32_32x32x16_bf16(vf11, pf[1], Ot1, 0, 0, 0);
          __builtin_amdgcn_s_setprio(0);
        }
      }
      cur ^= 1;
    }
    // ---- epilogue ----
    const float inv = 1.f / l_run;
    unsigned short* orow = ob + (bS + q_glob) * 2048 + h * 64;
#pragma unroll
    for (int j = 0; j < 4; ++j) {
      uint2 pr;
      pr.x = (unsigned int)f2b(Ot0[4 * j + 0] * inv) | ((unsigned int)f2b(Ot0[4 * j + 1] * inv) << 16);
      pr.y = (unsigned int)f2b(Ot0[4 * j + 2] * inv) | ((unsigned int)f2b(Ot0[4 * j + 3] * inv) << 16);
      *(uint2*)(orow + 8 * j + 4 * half) = pr;
      uint2 pr2;
      pr2.x = (unsigned int)f2b(Ot1[4 * j + 0] * inv) | ((unsigned int)f2b(Ot1[4 * j + 1] * inv) << 16);
      pr2.y = (unsigned int)f2b(Ot1[4 * j + 2] * inv) | ((unsigned int)f2b(Ot1[4 * j + 3] * inv) << 16);
      *(uint2*)(orow + 32 + 8 * j + 4 * half) = pr2;
    }
  }
}

extern "C" void kernel_launch(void* const* d_in, const int* in_sizes, int n_in,
                              void* d_out, int out_size, void* d_ws, size_t ws_size,
                              hipStream_t stream) {
  (void)in_sizes; (void)n_in; (void)out_size; (void)ws_size;
  const void* x  = d_in[0];
  const void* wq = d_in[1];
  const void* wk = d_in[2];
  const void* wv = d_in[3];
  const void* wo = d_in[4];
  unsigned short* ws = (unsigned short*)d_ws;

  int* FLAG = (int*)ws;
  unsigned short* WT  = ws + 128;
  unsigned short* WOT = WT  + (size_t)3072 * 2048;
  unsigned short* QKV = WOT + (size_t)2048 * 2048;
  unsigned short* VT  = QKV + (size_t)4096 * 3072;
  unsigned short* OB  = VT  + (size_t)16 * 64 * 2048;
  unsigned short* XB  = OB;  // x-as-bf16 (disjoint lifetime vs OB)

  detect_dtype<<<1, 64, 0, stream>>>((const unsigned short*)x, FLAG);

  transpose_w<<<dim3(32, 32), 256, 0, stream>>>(wq, 2048, 2048, WT, FLAG);
  transpose_w<<<dim3(8, 32), 256, 0, stream>>>(wk, 2048, 512, WT + (size_t)2048 * 2048, FLAG);
  transpose_w<<<dim3(8, 32), 256, 0, stream>>>(wv, 2048, 512, WT + (size_t)2560 * 2048, FLAG);
  transpose_w<<<dim3(32, 32), 256, 0, stream>>>(wo, 2048, 2048, WOT, FLAG);
  convert_x<<<4096, 256, 0, stream>>>(x, XB, FLAG);

  gemm_bt<<<dim3(24, 32), 256, 0, stream>>>(XB, WT, QKV, 4096, 3072, 2048, 2048, nullptr);
  transpose_v<<<dim3(32, 1, 16), 256, 0, stream>>>(QKV, VT);
  attn_fwd4<<<dim3(16, 32, 2), 128, 0, stream>>>(QKV, VT, OB);
  gemm_bt<<<dim3(16, 32), 256, 0, stream>>>(OB, WOT, d_out, 4096, 2048, 2048, 0, FLAG);
}